// Round 1
// baseline (114.109 us; speedup 1.0000x reference)
//
#include <hip/hip_runtime.h>
#include <cmath>

#define EPSN 1e-12f

// ---------------- Kernel A: L2-normalize query rows (B*Lq = 2048 rows of 128) --
__global__ __launch_bounds__(256) void qnorm_kernel(const float* __restrict__ qr,
                                                    float* __restrict__ qn) {
    int w = threadIdx.x >> 6;
    int lane = threadIdx.x & 63;
    int row = blockIdx.x * 4 + w;                 // 512 blocks * 4 waves = 2048 rows
    const float2* src = (const float2*)(qr + (size_t)row * 128);
    float2 v = src[lane];
    float ss = v.x * v.x + v.y * v.y;
#pragma unroll
    for (int off = 32; off; off >>= 1) ss += __shfl_xor(ss, off);
    float inv = 1.0f / fmaxf(sqrtf(ss), EPSN);
    float2 o; o.x = v.x * inv; o.y = v.y * inv;
    ((float2*)(qn + (size_t)row * 128))[lane] = o;
}

// ---------------- Kernel B: per-(b,n) scores ----------------------------------
// scores[b][n] = sum_q max_l dot(qn[b,q,:], normalize(doc[b,n,l,:]*mask))
// grid = 1024 blocks (one per (b,n)), 256 threads (4 waves).
// Wave w owns query rows 8w..8w+7. Lane owns doc token (chunk_base + lane).
__global__ __launch_bounds__(256, 3) void scores_kernel(
    const float* __restrict__ qn, const float* __restrict__ doc,
    const int* __restrict__ mask, float* __restrict__ scores) {
    __shared__ __align__(16) float qT[128 * 36];   // qT[d*36 + q], stride 36 keeps b128 aligned
    __shared__ __align__(16) float dS[64 * 128];   // XOR-swizzled token rows
    __shared__ float invS[64];
    __shared__ float wsum[4];

    int t = threadIdx.x;
    int bn = blockIdx.x;
    int b = bn >> 4;
    int w = t >> 6, lane = t & 63;

    // ---- stage queries transposed (one-time, 16 KB) ----
    const float4* q4 = (const float4*)(qn + (size_t)b * 32 * 128);
#pragma unroll
    for (int k = 0; k < 4; ++k) {
        int j = t + k * 256;          // float4 index into 32x128 tile
        float4 v = q4[j];
        int flat = j * 4;
        int q = flat >> 7;
        int d = flat & 127;
        qT[(d + 0) * 36 + q] = v.x;
        qT[(d + 1) * 36 + q] = v.y;
        qT[(d + 2) * 36 + q] = v.z;
        qT[(d + 3) * 36 + q] = v.w;
    }

    float rm[8];
#pragma unroll
    for (int q = 0; q < 8; ++q) rm[q] = -INFINITY;

    const float4* d4base = (const float4*)(doc) + (size_t)bn * 8192; // 256*128/4
    const int* mbase = mask + bn * 256;

    for (int c = 0; c < 4; ++c) {
        __syncthreads();   // previous chunk fully consumed (and qT staged, iter 0)

        // ---- stage 64 doc tokens (32 KB), XOR-swizzled slots ----
#pragma unroll
        for (int k = 0; k < 8; ++k) {
            int j = t + k * 256;                  // float4 idx in chunk (2048)
            float4 v = d4base[c * 2048 + j];
            int l = j >> 5, s = j & 31;           // token row, 16B slot
            int off = l * 128 + ((s ^ (l & 7)) << 2);
            *(float4*)&dS[off] = v;
        }
        __syncthreads();

        // ---- per-token inverse norms (4 threads per token) ----
        {
            int token = t >> 2, qtr = t & 3;
            float ss = 0.f;
#pragma unroll
            for (int i = 0; i < 8; ++i) {
                int s = qtr * 8 + i;
                int off = token * 128 + ((s ^ (token & 7)) << 2);
                float4 v = *(const float4*)&dS[off];
                ss += v.x * v.x + v.y * v.y + v.z * v.z + v.w * v.w;
            }
            ss += __shfl_xor(ss, 1);
            ss += __shfl_xor(ss, 2);
            if (qtr == 0) {
                int m = mbase[c * 64 + token];
                invS[token] = m ? (1.0f / fmaxf(sqrtf(ss), EPSN)) : 0.0f;
            }
        }
        __syncthreads();

        // ---- compute: 8 query rows (this wave) x own token, K=128 ----
        float acc[8];
#pragma unroll
        for (int q = 0; q < 8; ++q) acc[q] = 0.f;
        int dOff = lane * 128;
        int xr = (lane & 7) << 2;
#pragma unroll
        for (int s = 0; s < 32; ++s) {
            float4 dv = *(const float4*)&dS[dOff + ((s << 2) ^ xr)];
#pragma unroll
            for (int jj = 0; jj < 4; ++jj) {
                const float* qp = &qT[(4 * s + jj) * 36 + 8 * w];
                float4 qlo = *(const float4*)(qp);
                float4 qhi = *(const float4*)(qp + 4);
                float dj = jj == 0 ? dv.x : jj == 1 ? dv.y : jj == 2 ? dv.z : dv.w;
                acc[0] = fmaf(qlo.x, dj, acc[0]);
                acc[1] = fmaf(qlo.y, dj, acc[1]);
                acc[2] = fmaf(qlo.z, dj, acc[2]);
                acc[3] = fmaf(qlo.w, dj, acc[3]);
                acc[4] = fmaf(qhi.x, dj, acc[4]);
                acc[5] = fmaf(qhi.y, dj, acc[5]);
                acc[6] = fmaf(qhi.z, dj, acc[6]);
                acc[7] = fmaf(qhi.w, dj, acc[7]);
            }
        }
        float inv = invS[lane];
#pragma unroll
        for (int q = 0; q < 8; ++q) rm[q] = fmaxf(rm[q], acc[q] * inv);
    }

    // ---- reduce: max over 64 lanes (tokens) per q, sum 8 q's per wave ----
    float part = 0.f;
#pragma unroll
    for (int q = 0; q < 8; ++q) {
        float v = rm[q];
#pragma unroll
        for (int off = 32; off; off >>= 1) v = fmaxf(v, __shfl_xor(v, off));
        part += v;
    }
    if (lane == 0) wsum[w] = part;
    __syncthreads();
    if (t == 0) scores[bn] = wsum[0] + wsum[1] + wsum[2] + wsum[3];
}

// ---------------- Kernel C: pairwise ranking loss -> scalar -------------------
__global__ __launch_bounds__(256) void loss_kernel(const float* __restrict__ scores,
                                                   const float* __restrict__ labels,
                                                   float* __restrict__ out) {
    __shared__ float wsum[4];
    int t = threadIdx.x;
    float total = 0.f;
    for (int p = t; p < 64 * 256; p += 256) {
        int b = p >> 8;
        int ij = p & 255;
        int i = ij >> 4, j = ij & 15;
        float ysi = labels[b * 32 + i];
        float ysj = labels[b * 32 + j];
        if (ysi - ysj > 0.f) {
            float wgt = fabsf(labels[b * 32 + 16 + i] - labels[b * 32 + 16 + j]);
            float d = (i <= j) ? (scores[b * 16 + i] - scores[b * 16 + j]) : 0.f;
            total += log1pf(expf(-d)) * wgt;
        }
    }
#pragma unroll
    for (int off = 32; off; off >>= 1) total += __shfl_xor(total, off);
    int w = t >> 6, lane = t & 63;
    if (lane == 0) wsum[w] = total;
    __syncthreads();
    if (t == 0) out[0] = wsum[0] + wsum[1] + wsum[2] + wsum[3];
}

// ---------------- launch ------------------------------------------------------
extern "C" void kernel_launch(void* const* d_in, const int* in_sizes, int n_in,
                              void* d_out, int out_size, void* d_ws, size_t ws_size,
                              hipStream_t stream) {
    const float* qr     = (const float*)d_in[0];   // (64,32,128) f32
    const float* doc    = (const float*)d_in[1];   // (64,16,256,128) f32
    const int*   dmask  = (const int*)d_in[2];     // (64,16,256) i32
    const float* labels = (const float*)d_in[3];   // (64,32) f32
    float* out = (float*)d_out;                    // scalar f32

    float* qn     = (float*)d_ws;                  // 262144 f32 (1 MB)
    float* scores = qn + 64 * 32 * 128;            // 1024 f32

    qnorm_kernel<<<512, 256, 0, stream>>>(qr, qn);
    scores_kernel<<<1024, 256, 0, stream>>>(qn, doc, dmask, scores);
    loss_kernel<<<1, 256, 0, stream>>>(scores, labels, out);
}

// Round 2
// 52.523 us; speedup vs baseline: 2.1725x; 2.1725x over previous
//
#include <hip/hip_runtime.h>
#include <cmath>

#define EPSN 1e-12f

typedef _Float16 half8 __attribute__((ext_vector_type(8)));
typedef float f32x4 __attribute__((ext_vector_type(4)));

// ---------------------------------------------------------------------------
// Kernel A: per-b. Normalize q rows in fp32, split into f16 hi/lo, store as
// MFMA A-fragment image. qimg layout (halves):
//   [b][qtile(2)][kstep(4)][hl(2)][lane(64)][e(8)]   (8192 halves / b)
// A-frag convention (16x16x32): element (row,k): lane=(k>>3)*16+row, e=k&7.
// ---------------------------------------------------------------------------
__global__ __launch_bounds__(256) void qprep_kernel(const float* __restrict__ qr,
                                                    unsigned short* __restrict__ qimg) {
    int b = blockIdx.x, t = threadIdx.x;
    int row = t >> 3, jb = t & 7;          // 8 threads per row, 16 elems each
    const float4* src = (const float4*)(qr + ((size_t)b * 32 + row) * 128 + jb * 16);
    float4 v[4];
#pragma unroll
    for (int i = 0; i < 4; ++i) v[i] = src[i];
    float ss = 0.f;
#pragma unroll
    for (int i = 0; i < 4; ++i) ss += v[i].x*v[i].x + v[i].y*v[i].y + v[i].z*v[i].z + v[i].w*v[i].w;
    ss += __shfl_xor(ss, 1); ss += __shfl_xor(ss, 2); ss += __shfl_xor(ss, 4);
    float inv = 1.0f / fmaxf(sqrtf(ss), EPSN);
    float f[16];
#pragma unroll
    for (int i = 0; i < 4; ++i) {
        f[4*i+0] = v[i].x * inv; f[4*i+1] = v[i].y * inv;
        f[4*i+2] = v[i].z * inv; f[4*i+3] = v[i].w * inv;
    }
#pragma unroll
    for (int kh = 0; kh < 2; ++kh) {
        half8 hh, hl;
#pragma unroll
        for (int e = 0; e < 8; ++e) {
            float x = f[kh*8 + e];
            _Float16 h = (_Float16)x;
            hh[e] = h;
            hl[e] = (_Float16)(x - (float)h);
        }
        int k = jb*16 + kh*8;
        int kstep = k >> 5;
        int lanepos = (row & 15) + (((k & 31) >> 3) << 4);
        size_t off = (size_t)b * 8192 + (size_t)(((row>>4)*4 + kstep)*2) * 512 + lanepos * 8;
        *(half8*)(qimg + off)       = hh;   // hl=0 (hi)
        *(half8*)(qimg + off + 512) = hl;   // hl=1 (lo)
    }
}

// ---------------------------------------------------------------------------
// Kernel B: one block per (b,n). 256 threads = 4 waves; wave w owns token
// tiles 4w..4w+3 (64 tokens). K split into 4 chunks of 32; per chunk, thread t
// stages token t's 32 raw fp32 values -> f16 hi/lo B-fragment image in LDS,
// accumulating the exact fp32 sum-of-squares in a register. inv-norm applied
// in the epilogue (0 for masked tokens), then max over tokens / sum over q.
// ---------------------------------------------------------------------------
__global__ __launch_bounds__(256, 3) void scores_kernel(
    const unsigned short* __restrict__ qimg, const float* __restrict__ doc,
    const int* __restrict__ mask, float* __restrict__ scores) {
    __shared__ __align__(16) char Aimg[16384];   // [qtile2][kstep4][hl2][1024B]
    __shared__ __align__(16) char Bimg[32768];   // [tile16][hl2][1024B]
    __shared__ float invS[256];
    __shared__ float wq[4][32];

    int t = threadIdx.x, bn = blockIdx.x, b = bn >> 4;
    int w = t >> 6, lane = t & 63, col = lane & 15;
    int mtile = t >> 4, mcol = t & 15;           // this thread's token tile/col

    // stage A image (16 KB, once)
    {
        const float4* qs = (const float4*)(qimg + (size_t)b * 8192);
        float4* Ad = (float4*)Aimg;
#pragma unroll
        for (int i = 0; i < 4; ++i) Ad[i*256 + t] = qs[i*256 + t];
    }

    f32x4 acc[2][4];
    f32x4 zero = {0.f, 0.f, 0.f, 0.f};
#pragma unroll
    for (int qt = 0; qt < 2; ++qt)
#pragma unroll
        for (int nt = 0; nt < 4; ++nt) acc[qt][nt] = zero;

    const float4* dsrc = (const float4*)(doc + ((size_t)bn * 256 + t) * 128);
    float ss = 0.f;

    for (int c = 0; c < 4; ++c) {
        if (c) __syncthreads();                   // prev MFMA done before overwrite
        // ---- stage chunk c: thread t == token t, k in [32c, 32c+32) ----
        float4 r[8];
#pragma unroll
        for (int i = 0; i < 8; ++i) r[i] = dsrc[c*8 + i];
#pragma unroll
        for (int i = 0; i < 8; ++i)
            ss += r[i].x*r[i].x + r[i].y*r[i].y + r[i].z*r[i].z + r[i].w*r[i].w;
#pragma unroll
        for (int kg = 0; kg < 4; ++kg) {
            float xs[8] = { r[2*kg].x,   r[2*kg].y,   r[2*kg].z,   r[2*kg].w,
                            r[2*kg+1].x, r[2*kg+1].y, r[2*kg+1].z, r[2*kg+1].w };
            half8 hh, hl;
#pragma unroll
            for (int e = 0; e < 8; ++e) {
                float x = xs[e];
                _Float16 h = (_Float16)x;
                hh[e] = h;
                hl[e] = (_Float16)(x - (float)h);
            }
            int bo = ((mtile*2 + 0) << 10) + (kg*16 + mcol) * 16;
            *(half8*)(Bimg + bo)        = hh;
            *(half8*)(Bimg + bo + 1024) = hl;
        }
        if (c == 3) {
            int m = mask[bn * 256 + t];
            invS[t] = m ? (1.0f / fmaxf(sqrtf(ss), EPSN)) : 0.0f;
        }
        __syncthreads();
        // ---- MFMA: 2 q-tiles x 4 tok-tiles x (3 hi/lo terms) ----
        int lo = lane << 4;
        half8 a0h = *(const half8*)(Aimg + ((c*2 + 0) << 10) + lo);
        half8 a0l = *(const half8*)(Aimg + ((c*2 + 1) << 10) + lo);
        half8 a1h = *(const half8*)(Aimg + (((4 + c)*2 + 0) << 10) + lo);
        half8 a1l = *(const half8*)(Aimg + (((4 + c)*2 + 1) << 10) + lo);
#pragma unroll
        for (int nt = 0; nt < 4; ++nt) {
            int tile = w*4 + nt;
            half8 bh = *(const half8*)(Bimg + ((tile*2 + 0) << 10) + lo);
            half8 bl = *(const half8*)(Bimg + ((tile*2 + 1) << 10) + lo);
            acc[0][nt] = __builtin_amdgcn_mfma_f32_16x16x32_f16(a0l, bh, acc[0][nt], 0, 0, 0);
            acc[0][nt] = __builtin_amdgcn_mfma_f32_16x16x32_f16(a0h, bl, acc[0][nt], 0, 0, 0);
            acc[0][nt] = __builtin_amdgcn_mfma_f32_16x16x32_f16(a0h, bh, acc[0][nt], 0, 0, 0);
            acc[1][nt] = __builtin_amdgcn_mfma_f32_16x16x32_f16(a1l, bh, acc[1][nt], 0, 0, 0);
            acc[1][nt] = __builtin_amdgcn_mfma_f32_16x16x32_f16(a1h, bl, acc[1][nt], 0, 0, 0);
            acc[1][nt] = __builtin_amdgcn_mfma_f32_16x16x32_f16(a1h, bh, acc[1][nt], 0, 0, 0);
        }
    }

    // ---- epilogue: scale by inv-norm, max over tokens, sum over q ----
    float inv[4];
#pragma unroll
    for (int nt = 0; nt < 4; ++nt) inv[nt] = invS[w*64 + nt*16 + col];
    float m8[8];
#pragma unroll
    for (int qt = 0; qt < 2; ++qt)
#pragma unroll
        for (int rg = 0; rg < 4; ++rg) {
            float mv = -INFINITY;
#pragma unroll
            for (int nt = 0; nt < 4; ++nt) mv = fmaxf(mv, acc[qt][nt][rg] * inv[nt]);
            m8[qt*4 + rg] = mv;
        }
#pragma unroll
    for (int off = 1; off < 16; off <<= 1)
#pragma unroll
        for (int i = 0; i < 8; ++i) m8[i] = fmaxf(m8[i], __shfl_xor(m8[i], off));
    if (col == 0) {
        int rg = lane >> 4;   // C/D row group: row = rg*4 + reg
#pragma unroll
        for (int qt = 0; qt < 2; ++qt)
#pragma unroll
            for (int rr = 0; rr < 4; ++rr) wq[w][qt*16 + rg*4 + rr] = m8[qt*4 + rr];
    }
    __syncthreads();
    if (w == 0) {
        float v = 0.f;
        if (lane < 32)
            v = fmaxf(fmaxf(wq[0][lane], wq[1][lane]), fmaxf(wq[2][lane], wq[3][lane]));
#pragma unroll
        for (int off = 1; off < 64; off <<= 1) v += __shfl_xor(v, off);
        if (lane == 0) scores[bn] = v;
    }
}

// ---------------------------------------------------------------------------
// Kernel C: loss. One block per b (256 pairs), then 1-wave final reduce.
// ---------------------------------------------------------------------------
__global__ __launch_bounds__(256) void lossb_kernel(const float* __restrict__ scores,
                                                    const float* __restrict__ labels,
                                                    float* __restrict__ partial) {
    __shared__ float ys[16], idx[16], sc[16];
    __shared__ float wsum[4];
    int b = blockIdx.x, t = threadIdx.x;
    if (t < 16) {
        ys[t]  = labels[b*32 + t];
        idx[t] = labels[b*32 + 16 + t];
        sc[t]  = scores[b*16 + t];
    }
    __syncthreads();
    int i = t >> 4, j = t & 15;
    float v = 0.f;
    if (ys[i] - ys[j] > 0.f) {
        float wgt = fabsf(idx[i] - idx[j]);
        float d = (i <= j) ? (sc[i] - sc[j]) : 0.f;   // triu keeps i<=j; others diff=0
        v = log1pf(expf(-d)) * wgt;
    }
#pragma unroll
    for (int off = 1; off < 64; off <<= 1) v += __shfl_xor(v, off);
    int w = t >> 6, lane = t & 63;
    if (lane == 0) wsum[w] = v;
    __syncthreads();
    if (t == 0) partial[b] = wsum[0] + wsum[1] + wsum[2] + wsum[3];
}

__global__ void lossfin_kernel(const float* __restrict__ partial, float* __restrict__ out) {
    int t = threadIdx.x;   // 64 threads, one wave
    float v = partial[t];
#pragma unroll
    for (int off = 1; off < 64; off <<= 1) v += __shfl_xor(v, off);
    if (t == 0) out[0] = v;
}

// ---------------------------------------------------------------------------
extern "C" void kernel_launch(void* const* d_in, const int* in_sizes, int n_in,
                              void* d_out, int out_size, void* d_ws, size_t ws_size,
                              hipStream_t stream) {
    const float* qr     = (const float*)d_in[0];   // (64,32,128) f32
    const float* doc    = (const float*)d_in[1];   // (64,16,256,128) f32
    const int*   dmask  = (const int*)d_in[2];     // (64,16,256) i32
    const float* labels = (const float*)d_in[3];   // (64,32) f32
    float* out = (float*)d_out;

    unsigned short* qimg = (unsigned short*)d_ws;                    // 64*8192 halves = 1 MB
    float* scores  = (float*)((char*)d_ws + (size_t)64*8192*2);      // 1024 f32
    float* partial = scores + 1024;                                  // 64 f32

    qprep_kernel<<<64, 256, 0, stream>>>(qr, qimg);
    scores_kernel<<<1024, 256, 0, stream>>>(qimg, doc, dmask, scores);
    lossb_kernel<<<64, 256, 0, stream>>>(scores, labels, partial);
    lossfin_kernel<<<1, 64, 0, stream>>>(partial, out);
}